// Round 6
// baseline (164.497 us; speedup 1.0000x reference)
//
#include <hip/hip_runtime.h>

// Problem constants: h[B,G,D], W[G,D,K], out[B,G,K]
#define Gn   100
#define Bn   256
#define Dn   768
#define Kn   128

typedef __attribute__((ext_vector_type(8))) short short8;
typedef __attribute__((ext_vector_type(4))) float f32x4;

// pack two fp32 -> two bf16 (round-to-nearest, ties away) in 3 VALU
__device__ inline unsigned pack2(float lo, float hi) {
  union { float f; unsigned u; } a, b; a.f = lo; b.f = hi;
  return __builtin_amdgcn_perm(b.u + 0x8000u, a.u + 0x8000u, 0x07060302u);
}

// Async global->LDS DMA, 16B per lane. LDS dest must be wave-uniform base
// (HW adds lane*16); global src is per-lane.
__device__ inline void gload16(const float* g, float* l) {
  __builtin_amdgcn_global_load_lds(
      (const __attribute__((address_space(1))) void*)g,
      (__attribute__((address_space(3))) void*)l, 16, 0, 0);
}

// R6: staging moved OFF the wave: global_load_lds DMA of RAW FP32 tiles,
// bf16 conversion at fragment-build time (VALU was 90% idle). Rationale:
// R0/R3/R4/R5 all plateau ~55us with every pipe <16% busy; reg-staged
// prefetch at any depth leaves a ~7k cyc/step vmcnt stall on the wave's
// in-order stream. DMA staging pays only a counted vmcnt(8) (issue depth 2,
// 4 LDS buffers) and never drains in-loop (T3/T4, m97/m201 pattern).
// Bank conflicts fixed per rule 21 (both-sides swizzle): linear LDS dest,
// inverse-swizzled GLOBAL source, swizzled read. A[128][32] fp32: chunk ^=
// (row&7) (16-way -> 2-way, free). B[32][128] fp32: chunk ^= (k>>3)<<2
// (4-way quad collision -> 2-way, free). Norm ssq rides on fragment reads:
// waves wn==0 accumulate A-ssq, wm==0 B-ssq -- each element exactly once.
__global__ __launch_bounds__(512, 2) void groupfc_kernel(
    const float* __restrict__ h, const float* __restrict__ W,
    float* __restrict__ out) {
  // grid 208 = 8*26; decode: xcd=id%8 -> g%8, j=id>>3: mt=j&1, g=xcd+8*(j>>1)
  const int id  = blockIdx.x;
  const int xcd = id & 7;
  const int j   = id >> 3;                   // 0..25
  const int mt  = j & 1;                     // 0..1 (rows of 128)
  const int g   = xcd + (j >> 1) * 8;        // 0..103
  if (g >= Gn) return;                       // pad blocks exit before any barrier

  const int t    = threadIdx.x;
  const int lane = t & 63;
  const int w    = t >> 6;                   // wave 0..7
  const int wm   = w >> 2;                   // 0..1 (64-row halves)
  const int wn   = w & 3;                    // 0..3 (32-col quarters)
  const int l15  = lane & 15, quad = lane >> 4;

  // 4 buffers x (A 16KB + B 16KB) fp32 = 128KB; + norms 1KB.
  __shared__ __align__(16) float Af[4][128 * 32];  // [row][kchunk swz] fp32
  __shared__ __align__(16) float Bf[4][32 * 128];  // [k][colchunk swz] fp32
  __shared__ float AssqL[128];
  __shared__ float BssqL[128];

  f32x4 acc[4][2];
#pragma unroll
  for (int mi = 0; mi < 4; ++mi)
#pragma unroll
    for (int ni = 0; ni < 2; ++ni) acc[mi][ni] = (f32x4){0.f, 0.f, 0.f, 0.f};

  // ---- DMA staging setup ----
  // A call q in {0,1}: dest row r = w*16 + q*8 + (l>>3), dest chunk l&7
  //   (LDS floats: w*512 + q*256 + lane*4). Source k-chunk = (l&7)^(r&7).
  const int arow0 = w * 16 + (lane >> 3);
  const int axor  = (lane & 7) ^ ((lane >> 3) & 7);   // r&7 == (l>>3)&7
  const float* asrc0 = h + ((size_t)(mt * 128 + arow0) * Gn + g) * Dn + 4 * axor;
  const float* asrc1 = h + ((size_t)(mt * 128 + arow0 + 8) * Gn + g) * Dn + 4 * axor;
  // B call q: dest d-row dd = w*4 + q*2 + (l>>5), dest chunk l&31.
  //   Source col-chunk = (l&31) ^ ((dd>>3)<<2).
  const float* Wg = W + (size_t)g * (Dn * Kn);
  const int dd0 = w * 4 + (lane >> 5);
  const int dd1 = dd0 + 2;
  const float* bsrc0 = Wg + (size_t)dd0 * Kn + 4 * ((lane & 31) ^ ((dd0 >> 3) << 2));
  const float* bsrc1 = Wg + (size_t)dd1 * Kn + 4 * ((lane & 31) ^ ((dd1 >> 3) << 2));
  const int ldsq = w * 512;                  // per-wave LDS float base (q0); q1 +256

  auto issue = [&](int tile, float* AbW, float* BbW) {
    const size_t ad = (size_t)tile * 32;
    const size_t bd = (size_t)tile * 32 * Kn;
    gload16(asrc0 + ad, AbW + ldsq);
    gload16(asrc1 + ad, AbW + ldsq + 256);
    gload16(bsrc0 + bd, BbW + ldsq);
    gload16(bsrc1 + bd, BbW + ldsq + 256);
  };

  // ---- fragment read addressing (swizzled) ----
  // A frag (mi,i): row = wm*64 + mi*16 + l15, kchunk = (quad*2+i)^(l15&7)
  const int aBase = (wm * 64 + l15) * 32;
  const int ac0   = ((quad * 2) ^ (l15 & 7)) * 4;
  const int ac1   = ((quad * 2 + 1) ^ (l15 & 7)) * 4;
  // B frag (ni,j): k = quad*8+j, col = wn*32+ni*16+l15:
  //   idx = k*128 + ((col>>2)^(quad<<2))*4 + (col&3)
  const int col0 = wn * 32 + l15;
  const int col1 = col0 + 16;
  const int b0   = quad * 1024 + (((col0 >> 2) ^ (quad << 2)) << 2) + (l15 & 3);
  const int b1   = quad * 1024 + (((col1 >> 2) ^ (quad << 2)) << 2) + (l15 & 3);

  float asq[4] = {0.f, 0.f, 0.f, 0.f};
  float bsq[2] = {0.f, 0.f};

  auto compute = [&](const float* Ab, const float* Bb) {
    short8 af[4], bf[2];
#pragma unroll
    for (int mi = 0; mi < 4; ++mi) {
      const f32x4 x0 = *(const f32x4*)&Ab[aBase + mi * 512 + ac0];
      const f32x4 x1 = *(const f32x4*)&Ab[aBase + mi * 512 + ac1];
      union { uint4 u; short8 s; } r;
      r.u.x = pack2(x0.x, x0.y); r.u.y = pack2(x0.z, x0.w);
      r.u.z = pack2(x1.x, x1.y); r.u.w = pack2(x1.z, x1.w);
      af[mi] = r.s;
      if (wn == 0)
        asq[mi] += x0.x*x0.x + x0.y*x0.y + x0.z*x0.z + x0.w*x0.w
                 + x1.x*x1.x + x1.y*x1.y + x1.z*x1.z + x1.w*x1.w;
    }
#pragma unroll
    for (int ni = 0; ni < 2; ++ni) {
      const int bb = ni ? b1 : b0;
      float z0 = Bb[bb],           z1 = Bb[bb + 128],
            z2 = Bb[bb + 2 * 128], z3 = Bb[bb + 3 * 128],
            z4 = Bb[bb + 4 * 128], z5 = Bb[bb + 5 * 128],
            z6 = Bb[bb + 6 * 128], z7 = Bb[bb + 7 * 128];
      union { uint4 u; short8 s; } r;
      r.u.x = pack2(z0, z1); r.u.y = pack2(z2, z3);
      r.u.z = pack2(z4, z5); r.u.w = pack2(z6, z7);
      bf[ni] = r.s;
      if (wm == 0)
        bsq[ni] += z0*z0 + z1*z1 + z2*z2 + z3*z3 + z4*z4 + z5*z5 + z6*z6 + z7*z7;
    }
#pragma unroll
    for (int mi = 0; mi < 4; ++mi)
#pragma unroll
      for (int ni = 0; ni < 2; ++ni)
        acc[mi][ni] = __builtin_amdgcn_mfma_f32_16x16x32_bf16(
            af[mi], bf[ni], acc[mi][ni], 0, 0, 0);
  };

#define VMW(N) asm volatile("s_waitcnt vmcnt(" #N ")" ::: "memory")
#define BAR()  asm volatile("s_barrier" ::: "memory")

  // ---- prologue: tiles 0,1 in flight ----
  issue(0, Af[0], Bf[0]);
  issue(1, Af[1], Bf[1]);

  // ---- main loop: iter t reads buf t%4, issues tile t+2 -> buf (t+2)%4.
  // Write target (t+2)%4 == (t-2)%4: disjoint from bufs read in current
  // (t%4) and previous ((t-1)%4) windows -- no read/DMA race. vmcnt(8):
  // tiles t+1,t+2 (4 calls each) may remain in flight; tile t is complete.
  for (int tt = 0; tt < 20; tt += 4) {
    issue(tt + 2, Af[2], Bf[2]); VMW(8); BAR(); compute(Af[0], Bf[0]);
    issue(tt + 3, Af[3], Bf[3]); VMW(8); BAR(); compute(Af[1], Bf[1]);
    issue(tt + 4, Af[0], Bf[0]); VMW(8); BAR(); compute(Af[2], Bf[2]);
    issue(tt + 5, Af[1], Bf[1]); VMW(8); BAR(); compute(Af[3], Bf[3]);
  }
  // tail: t = 20..23 (tiles 22,23 issued; then drain 8 -> 4 -> 0)
  issue(22, Af[2], Bf[2]); VMW(8); BAR(); compute(Af[0], Bf[0]);
  issue(23, Af[3], Bf[3]); VMW(8); BAR(); compute(Af[1], Bf[1]);
  VMW(4); BAR(); compute(Af[2], Bf[2]);
  VMW(0); BAR(); compute(Af[3], Bf[3]);

#undef VMW
#undef BAR

  // ---- norm reduction (ssq accumulated on fragment reads) ----
  if (wn == 0) {                             // waves 0,4: A rows wm*64..+63
#pragma unroll
    for (int mi = 0; mi < 4; ++mi) {
      asq[mi] += __shfl_xor(asq[mi], 16);
      asq[mi] += __shfl_xor(asq[mi], 32);
      if (quad == 0) AssqL[wm * 64 + mi * 16 + l15] = asq[mi];
    }
  }
  if (wm == 0) {                             // waves 0..3: B cols wn*32..+31
#pragma unroll
    for (int ni = 0; ni < 2; ++ni) {
      bsq[ni] += __shfl_xor(bsq[ni], 16);
      bsq[ni] += __shfl_xor(bsq[ni], 32);
      if (quad == 0) BssqL[wn * 32 + ni * 16 + l15] = bsq[ni];
    }
  }
  __syncthreads();                           // one draining barrier: loop done

  // ---- epilogue: scale by 1/max(||h_row||,eps) * 1/max(||w_col||,eps) ----
  // C/D layout: col = lane&15, row = quad*4 + reg
  const float wi0 = 1.0f / fmaxf(sqrtf(BssqL[col0]), 1e-12f);
  const float wi1 = 1.0f / fmaxf(sqrtf(BssqL[col1]), 1e-12f);

#pragma unroll
  for (int mi = 0; mi < 4; ++mi) {
#pragma unroll
    for (int r = 0; r < 4; ++r) {
      const int lr = wm * 64 + mi * 16 + quad * 4 + r;   // local row in tile
      const float hs = 1.0f / fmaxf(sqrtf(AssqL[lr]), 1e-12f);
      const int row = mt * 128 + lr;
      const size_t ob = ((size_t)row * Gn + g) * Kn;
      out[ob + col0] = acc[mi][0][r] * hs * wi0;
      out[ob + col1] = acc[mi][1][r] * hs * wi1;
    }
  }
}

extern "C" void kernel_launch(void* const* d_in, const int* in_sizes, int n_in,
                              void* d_out, int out_size, void* d_ws, size_t ws_size,
                              hipStream_t stream) {
  const float* h = (const float*)d_in[0];          // [B,G,D]
  const float* W = (const float*)d_in[1];          // [G,D,K]
  float* out = (float*)d_out;                      // [B,G,K]
  hipLaunchKernelGGL(groupfc_kernel, dim3(208), dim3(512), 0, stream, h, W, out);
}